// Round 1
// baseline (1125.284 us; speedup 1.0000x reference)
//
#include <hip/hip_runtime.h>
#include <hip/hip_bf16.h>

#define MB 16
#define VN 8192
#define DK 512            // DIN == DOUT
#define NROWS (MB * VN)   // 131072

typedef __attribute__((ext_vector_type(8))) short bf16x8;
typedef __attribute__((ext_vector_type(4))) float f32x4;
typedef __attribute__((ext_vector_type(4))) int i32x4;
typedef __attribute__((ext_vector_type(2))) int i32x2;

static __device__ __forceinline__ short f2bf(float f) {
  union { float f; unsigned u; } a; a.f = f;
  unsigned r = a.u + 0x7FFFu + ((a.u >> 16) & 1u);  // RTNE
  return (short)(r >> 16);
}
static __device__ __forceinline__ int packbf2(float lo, float hi) {
  return (int)((unsigned)(unsigned short)f2bf(lo) | ((unsigned)(unsigned short)f2bf(hi) << 16));
}

// LDS byte address with XOR swizzle (G4): row in [0,128), byteoff in [0,128)
static __device__ __forceinline__ int swz(int row, int byteoff) {
  return row * 128 + (byteoff ^ ((row & 7) << 4));
}

// ---------------------------------------------------------------------------
// Kernel 1: QK GEMM.  A = latent [131072,512] f32.  Bt = [Wq;Wk] (n-major,
// k-contiguous, 1024 n-rows).  Out = [131072,1024] bf16 (cols 0-511 Q, 512+ K).
// ---------------------------------------------------------------------------
__global__ __launch_bounds__(256) void qk_gemm(
    const float* __restrict__ latent, const float* __restrict__ Wq,
    const float* __restrict__ bq, const float* __restrict__ Wk,
    const float* __restrict__ bk, unsigned short* __restrict__ outQK) {
  __shared__ i32x4 As4[128 * 8];
  __shared__ i32x4 Bs4[128 * 8];
  char* As = (char*)As4;
  char* Bs = (char*)Bs4;
  const int tid = threadIdx.x;
  const int bid = blockIdx.x;
  const int tn = bid & 7;    // 8 col tiles (N = 1024)
  const int tm = bid >> 3;   // 1024 row tiles
  const int rowbase = tm * 128;
  const int colbase = tn * 128;
  const int lane = tid & 63, wid = tid >> 6;
  const int wm = wid & 1, wn = wid >> 1;
  const int lrow = lane & 15, lhi = lane >> 4;

  f32x4 acc[4][4];
#pragma unroll
  for (int a = 0; a < 4; ++a)
#pragma unroll
    for (int b = 0; b < 4; ++b) acc[a][b] = (f32x4){0.f, 0.f, 0.f, 0.f};

  for (int kc = 0; kc < 8; ++kc) {
    const int k0 = kc * 64;
    if (kc) __syncthreads();
#pragma unroll
    for (int it = 0; it < 4; ++it) {
      int c = it * 256 + tid;
      int row = c >> 3, s = c & 7;
      const float* src = latent + (size_t)(rowbase + row) * DK + k0 + s * 8;
      float4 x0 = *(const float4*)src;
      float4 x1 = *(const float4*)(src + 4);
      i32x4 v = {packbf2(x0.x, x0.y), packbf2(x0.z, x0.w),
                 packbf2(x1.x, x1.y), packbf2(x1.z, x1.w)};
      *(i32x4*)(As + swz(row, s * 16)) = v;
    }
#pragma unroll
    for (int it = 0; it < 4; ++it) {
      int c = it * 256 + tid;
      int n = c >> 3, s = c & 7;
      int gn = colbase + n;
      const float* src =
          (gn < 512 ? Wq + (size_t)gn * DK : Wk + (size_t)(gn - 512) * DK) + k0 + s * 8;
      float4 x0 = *(const float4*)src;
      float4 x1 = *(const float4*)(src + 4);
      i32x4 v = {packbf2(x0.x, x0.y), packbf2(x0.z, x0.w),
                 packbf2(x1.x, x1.y), packbf2(x1.z, x1.w)};
      *(i32x4*)(Bs + swz(n, s * 16)) = v;
    }
    __syncthreads();
#pragma unroll
    for (int kk = 0; kk < 2; ++kk) {
      bf16x8 af[4], bfr[4];
#pragma unroll
      for (int mi = 0; mi < 4; ++mi) {
        int r = wm * 64 + mi * 16 + lrow;
        af[mi] = *(const bf16x8*)(As + swz(r, lhi * 16 + kk * 64));
      }
#pragma unroll
      for (int ni = 0; ni < 4; ++ni) {
        int r = wn * 64 + ni * 16 + lrow;
        bfr[ni] = *(const bf16x8*)(Bs + swz(r, lhi * 16 + kk * 64));
      }
#pragma unroll
      for (int mi = 0; mi < 4; ++mi)
#pragma unroll
        for (int ni = 0; ni < 4; ++ni)
          acc[mi][ni] = __builtin_amdgcn_mfma_f32_16x16x32_bf16(af[mi], bfr[ni],
                                                                acc[mi][ni], 0, 0, 0);
    }
  }
#pragma unroll
  for (int ni = 0; ni < 4; ++ni) {
    int gcol = colbase + wn * 64 + ni * 16 + lrow;
    float bias = gcol < 512 ? bq[gcol] : bk[gcol - 512];
#pragma unroll
    for (int mi = 0; mi < 4; ++mi) {
      int grow0 = rowbase + wm * 64 + mi * 16 + lhi * 4;
#pragma unroll
      for (int q = 0; q < 4; ++q) {
        float v = acc[mi][ni][q] + bias;
        outQK[(size_t)(grow0 + q) * 1024 + gcol] = (unsigned short)f2bf(v);
      }
    }
  }
}

// ---------------------------------------------------------------------------
// Kernel 2: Gram.  G[i,j] = sum_{v,d} Q[i,v,d]*K[j,v,d];  S[i] = ||Q_i||^2.
// MFMA straight from global (memory-bound). Atomic accumulate into ws.
// ---------------------------------------------------------------------------
__global__ __launch_bounds__(256) void gram_kernel(
    const unsigned short* __restrict__ QK, float* __restrict__ G,
    float* __restrict__ S) {
  const int tid = threadIdx.x;
  const int lane = tid & 63, wid = tid >> 6;
  const int wg = blockIdx.x * 4 + wid;  // 0..4095 (grid 1024)
  const int i16 = lane & 15, s = lane >> 4;
  f32x4 accG = {0.f, 0.f, 0.f, 0.f}, accS = {0.f, 0.f, 0.f, 0.f};
  for (int v = wg; v < VN; v += 4096) {
    const unsigned short* base = QK + (size_t)(i16 * VN + v) * 1024 + s * 8;
#pragma unroll
    for (int d0 = 0; d0 < 512; d0 += 32) {
      bf16x8 q = *(const bf16x8*)(base + d0);
      bf16x8 k = *(const bf16x8*)(base + 512 + d0);
      accG = __builtin_amdgcn_mfma_f32_16x16x32_bf16(q, k, accG, 0, 0, 0);
      accS = __builtin_amdgcn_mfma_f32_16x16x32_bf16(q, q, accS, 0, 0, 0);
    }
  }
  __shared__ float Gs[256];
  __shared__ float Ss[16];
  Gs[tid] = 0.f;
  if (tid < 16) Ss[tid] = 0.f;
  __syncthreads();
#pragma unroll
  for (int q = 0; q < 4; ++q) {
    int gi = s * 4 + q, gj = i16;  // C/D map: row=(lane>>4)*4+reg, col=lane&15
    atomicAdd(&Gs[gi * 16 + gj], accG[q]);
    if (gi == gj) atomicAdd(&Ss[gi], accS[q]);
  }
  __syncthreads();
  atomicAdd(&G[tid], Gs[tid]);
  if (tid < 16) atomicAdd(&S[tid], Ss[tid]);
}

// ---------------------------------------------------------------------------
// Kernel 3: P solve (1 block). sigmoid -> dual softmax avg -> 10x projection.
// ---------------------------------------------------------------------------
__global__ __launch_bounds__(256) void psolve(const float* __restrict__ G,
                                              const float* __restrict__ S,
                                              float* __restrict__ Pf,
                                              float* __restrict__ cvec) {
  __shared__ float P[256], T[256];
  const int t = threadIdx.x, i = t >> 4, j = t & 15;
  float x = G[t] / sqrtf(S[i]);  // nq_j == 1 to ~1e-6
  P[t] = 1.f / (1.f + expf(-x));
  __syncthreads();
  float m0 = -1e30f, m1 = -1e30f;
  for (int a = 0; a < 16; ++a) {
    m0 = fmaxf(m0, P[a * 16 + j]);
    m1 = fmaxf(m1, P[i * 16 + a]);
  }
  float s0 = 0.f, s1 = 0.f;
  for (int a = 0; a < 16; ++a) {
    s0 += expf(P[a * 16 + j] - m0);
    s1 += expf(P[i * 16 + a] - m1);
  }
  float pr = 0.5f * (expf(P[t] - m0) / s0 + expf(P[t] - m1) / s1);
  __syncthreads();
  P[t] = pr;
  __syncthreads();
  for (int it = 0; it < 10; ++it) {
    float p1 = fmaxf(P[t], 0.f);
    T[t] = p1;
    __syncthreads();
    float rs = 0.f;
    for (int a = 0; a < 16; ++a) rs += T[i * 16 + a];
    float p2 = p1 - (rs - 1.f) * 0.0625f;
    __syncthreads();
    T[t] = p2;
    __syncthreads();
    float cs = 0.f;
    for (int a = 0; a < 16; ++a) cs += T[a * 16 + j];
    float p3 = p2 - (cs - 1.f) * 0.0625f;
    __syncthreads();
    P[t] = p3;
    __syncthreads();
  }
  Pf[t] = P[t];
  if (t < 16) {
    float cc = 0.f;
    for (int a = 0; a < 16; ++a) cc += P[a * 16 + t];
    cvec[t] = cc;
  }
}

// ---------------------------------------------------------------------------
// Kernel 4: Lmix[j,v,d] = sum_i Pf[i,j] * latent[i,v,d]  (bf16 out, in ws)
// ---------------------------------------------------------------------------
__global__ __launch_bounds__(256) void mix_kernel(
    const float* __restrict__ latent, const float* __restrict__ Pf,
    unsigned short* __restrict__ Lmix) {
  __shared__ float Pl[256];
  Pl[threadIdx.x] = Pf[threadIdx.x];
  __syncthreads();
  const size_t plane = (size_t)VN * DK;  // 4194304
  size_t f = ((size_t)blockIdx.x * 256 + threadIdx.x) * 4;
  float4 acc[16];
#pragma unroll
  for (int jj = 0; jj < 16; ++jj) acc[jj] = make_float4(0.f, 0.f, 0.f, 0.f);
#pragma unroll
  for (int ii = 0; ii < 16; ++ii) {
    float4 xv = *(const float4*)(latent + (size_t)ii * plane + f);
#pragma unroll
    for (int jj = 0; jj < 16; ++jj) {
      float w = Pl[ii * 16 + jj];
      acc[jj].x += w * xv.x;
      acc[jj].y += w * xv.y;
      acc[jj].z += w * xv.z;
      acc[jj].w += w * xv.w;
    }
  }
#pragma unroll
  for (int jj = 0; jj < 16; ++jj) {
    i32x2 pv = {packbf2(acc[jj].x, acc[jj].y), packbf2(acc[jj].z, acc[jj].w)};
    *(i32x2*)(Lmix + (size_t)jj * plane + f) = pv;
  }
}

// ---------------------------------------------------------------------------
// Kernel 5: final = Lmix @ Wv^T + c_j * bv  ->  f32 d_out.
// MIXA fallback (small ws): build the A tile from latent on the fly.
// ---------------------------------------------------------------------------
template <bool MIXA>
__global__ __launch_bounds__(256) void final_gemm(
    const unsigned short* __restrict__ Lmix, const float* __restrict__ latent,
    const float* __restrict__ Wv, const float* __restrict__ bv,
    const float* __restrict__ cvec, const float* __restrict__ Pf,
    float* __restrict__ out) {
  __shared__ i32x4 As4[128 * 8];
  __shared__ i32x4 Bs4[128 * 8];
  char* As = (char*)As4;
  char* Bs = (char*)Bs4;
  const int tid = threadIdx.x;
  const int bid = blockIdx.x;
  const int tn = bid & 3;   // N = 512 -> 4 tiles
  const int tm = bid >> 2;  // 1024 row tiles
  const int rowbase = tm * 128, colbase = tn * 128;
  const int jbat = rowbase >> 13;   // 8192 rows per j
  const int vbase = rowbase & 8191;
  const int lane = tid & 63, wid = tid >> 6;
  const int wm = wid & 1, wn = wid >> 1;
  const int lrow = lane & 15, lhi = lane >> 4;

  float wmix[16];
  if (MIXA) {
#pragma unroll
    for (int ii = 0; ii < 16; ++ii) wmix[ii] = Pf[ii * 16 + jbat];
  }

  f32x4 acc[4][4];
#pragma unroll
  for (int a = 0; a < 4; ++a)
#pragma unroll
    for (int b = 0; b < 4; ++b) acc[a][b] = (f32x4){0.f, 0.f, 0.f, 0.f};

  for (int kc = 0; kc < 8; ++kc) {
    const int k0 = kc * 64;
    if (kc) __syncthreads();
#pragma unroll
    for (int it = 0; it < 4; ++it) {
      int c = it * 256 + tid;
      int row = c >> 3, s = c & 7;
      if (MIXA) {
        float a0 = 0.f, a1 = 0.f, a2 = 0.f, a3 = 0.f, a4 = 0.f, a5 = 0.f, a6 = 0.f, a7 = 0.f;
#pragma unroll
        for (int ii = 0; ii < 16; ++ii) {
          const float* src =
              latent + ((size_t)ii * VN + vbase + row) * DK + k0 + s * 8;
          float4 x0 = *(const float4*)src;
          float4 x1 = *(const float4*)(src + 4);
          float w = wmix[ii];
          a0 += w * x0.x; a1 += w * x0.y; a2 += w * x0.z; a3 += w * x0.w;
          a4 += w * x1.x; a5 += w * x1.y; a6 += w * x1.z; a7 += w * x1.w;
        }
        i32x4 v = {packbf2(a0, a1), packbf2(a2, a3), packbf2(a4, a5), packbf2(a6, a7)};
        *(i32x4*)(As + swz(row, s * 16)) = v;
      } else {
        i32x4 v = *(const i32x4*)(Lmix + (size_t)(rowbase + row) * DK + k0 + s * 8);
        *(i32x4*)(As + swz(row, s * 16)) = v;
      }
    }
#pragma unroll
    for (int it = 0; it < 4; ++it) {
      int c = it * 256 + tid;
      int n = c >> 3, s = c & 7;
      int gn = colbase + n;
      const float* src = Wv + (size_t)gn * DK + k0 + s * 8;
      float4 x0 = *(const float4*)src;
      float4 x1 = *(const float4*)(src + 4);
      i32x4 v = {packbf2(x0.x, x0.y), packbf2(x0.z, x0.w),
                 packbf2(x1.x, x1.y), packbf2(x1.z, x1.w)};
      *(i32x4*)(Bs + swz(n, s * 16)) = v;
    }
    __syncthreads();
#pragma unroll
    for (int kk = 0; kk < 2; ++kk) {
      bf16x8 af[4], bfr[4];
#pragma unroll
      for (int mi = 0; mi < 4; ++mi) {
        int r = wm * 64 + mi * 16 + lrow;
        af[mi] = *(const bf16x8*)(As + swz(r, lhi * 16 + kk * 64));
      }
#pragma unroll
      for (int ni = 0; ni < 4; ++ni) {
        int r = wn * 64 + ni * 16 + lrow;
        bfr[ni] = *(const bf16x8*)(Bs + swz(r, lhi * 16 + kk * 64));
      }
#pragma unroll
      for (int mi = 0; mi < 4; ++mi)
#pragma unroll
        for (int ni = 0; ni < 4; ++ni)
          acc[mi][ni] = __builtin_amdgcn_mfma_f32_16x16x32_bf16(af[mi], bfr[ni],
                                                                acc[mi][ni], 0, 0, 0);
    }
  }
  const float cj = cvec[jbat];
#pragma unroll
  for (int ni = 0; ni < 4; ++ni) {
    int gcol = colbase + wn * 64 + ni * 16 + lrow;
    float bias = cj * bv[gcol];
#pragma unroll
    for (int mi = 0; mi < 4; ++mi) {
      int grow0 = rowbase + wm * 64 + mi * 16 + lhi * 4;
#pragma unroll
      for (int q = 0; q < 4; ++q) {
        out[(size_t)(grow0 + q) * DK + gcol] = acc[mi][ni][q] + bias;
      }
    }
  }
}

// ---------------------------------------------------------------------------
extern "C" void kernel_launch(void* const* d_in, const int* in_sizes, int n_in,
                              void* d_out, int out_size, void* d_ws, size_t ws_size,
                              hipStream_t stream) {
  (void)in_sizes; (void)n_in; (void)out_size;
  const float* latent = (const float*)d_in[0];
  const float* Wq = (const float*)d_in[1];
  const float* bq = (const float*)d_in[2];
  const float* Wk = (const float*)d_in[3];
  const float* bk = (const float*)d_in[4];
  const float* Wv = (const float*)d_in[5];
  const float* bv = (const float*)d_in[6];

  float* G = (float*)d_ws;       // 256 f32
  float* S = G + 256;            // 16 f32
  float* Pf = G + 512;           // 256 f32
  float* cv = G + 768;           // 16 f32
  unsigned short* Lmix = (unsigned short*)((char*)d_ws + 4096);
  unsigned short* QK = (unsigned short*)d_out;  // [131072,1024] bf16, exactly fills d_out

  hipMemsetAsync(d_ws, 0, 1088, stream);  // zero G and S accumulators

  qk_gemm<<<8192, 256, 0, stream>>>(latent, Wq, bq, Wk, bk, QK);
  gram_kernel<<<1024, 256, 0, stream>>>(QK, G, S);
  psolve<<<1, 256, 0, stream>>>(G, S, Pf, cv);

  const bool big_ws = ws_size >= (size_t)4096 + (size_t)NROWS * DK * 2;
  if (big_ws) {
    mix_kernel<<<4096, 256, 0, stream>>>(latent, Pf, Lmix);
    final_gemm<false><<<4096, 256, 0, stream>>>(Lmix, latent, Wv, bv, cv, Pf,
                                                (float*)d_out);
  } else {
    final_gemm<true><<<4096, 256, 0, stream>>>(nullptr, latent, Wv, bv, cv, Pf,
                                               (float*)d_out);
  }
}